// Round 7
// baseline (163.355 us; speedup 1.0000x reference)
//
#include <hip/hip_runtime.h>

#define LN_EPS 1e-5f
#define D 768
#define D4 192          // D/4
#define TWO_D 1536

typedef float f4 __attribute__((ext_vector_type(4)));

// ---------------- Pass A: per-row gate weights (pure read stream) ----------
// One wave per row. Regular (cache-allocating) loads so seq/msa stay L3-hot
// for pass B. Computes logits via l_k = rstd*(A_k - mean*C_k) + E_k + gb_k,
// with C_k = sum(gamma*w_k), E_k = sum(beta*w_k) folded into the same
// 8-chain butterfly. Writes 8 B per row (softmax weights) to ws.
__global__ __launch_bounds__(256) void stats_kernel(
    const float* __restrict__ seq, const float* __restrict__ msa,
    const float* __restrict__ gamma, const float* __restrict__ beta,
    const float* __restrict__ gate_w, const float* __restrict__ gate_b,
    float* __restrict__ gate_ws, int nrows)
{
    const int wave = threadIdx.x >> 6;
    const int lane = threadIdx.x & 63;
    const int row = blockIdx.x * 4 + wave;
    if (row >= nrows) return;

    const f4* sp = (const f4*)(seq + (size_t)row * D);
    const f4* mp = (const f4*)(msa + (size_t)row * D);

    // data loads first (HBM, longest latency)
    f4 s[3], m[3];
    #pragma unroll
    for (int j = 0; j < 3; ++j) {
        s[j] = sp[j * 64 + lane];
        m[j] = mp[j * 64 + lane];
    }

    const f4* g4  = (const f4*)gamma;
    const f4* b4  = (const f4*)beta;
    const f4* w04 = (const f4*)gate_w;
    const f4* w14 = (const f4*)(gate_w + TWO_D);

    float su = 0.f, sq = 0.f, a0 = 0.f, a1 = 0.f;
    float C0 = 0.f, C1 = 0.f, E0 = 0.f, E1 = 0.f;
    #pragma unroll
    for (int j = 0; j < 6; ++j) {
        const int idx = (j < 3) ? (j * 64 + lane) : (D4 + (j - 3) * 64 + lane);
        const f4 g = g4[idx], bb = b4[idx], w0 = w04[idx], w1 = w14[idx];
        const f4 p0 = g * w0;
        const f4 p1 = g * w1;
        C0 += p0.x + p0.y + p0.z + p0.w;
        C1 += p1.x + p1.y + p1.z + p1.w;
        E0 += bb.x * w0.x + bb.y * w0.y + bb.z * w0.z + bb.w * w0.w;
        E1 += bb.x * w1.x + bb.y * w1.y + bb.z * w1.z + bb.w * w1.w;
        const f4 h = (j < 3) ? s[j] : m[j - 3];
        su += h.x + h.y + h.z + h.w;
        sq += h.x * h.x + h.y * h.y + h.z * h.z + h.w * h.w;
        a0 += h.x * p0.x + h.y * p0.y + h.z * p0.z + h.w * p0.w;
        a1 += h.x * p1.x + h.y * p1.y + h.z * p1.z + h.w * p1.w;
    }
    #pragma unroll
    for (int off = 32; off > 0; off >>= 1) {
        su += __shfl_xor(su, off, 64);
        sq += __shfl_xor(sq, off, 64);
        a0 += __shfl_xor(a0, off, 64);
        a1 += __shfl_xor(a1, off, 64);
        C0 += __shfl_xor(C0, off, 64);
        C1 += __shfl_xor(C1, off, 64);
        E0 += __shfl_xor(E0, off, 64);
        E1 += __shfl_xor(E1, off, 64);
    }

    if (lane == 0) {
        const float inv_n = 1.f / (float)TWO_D;
        const float mean = su * inv_n;
        const float var  = fmaxf(sq * inv_n - mean * mean, 0.f);
        const float rstd = rsqrtf(var + LN_EPS);
        const float l0 = rstd * (a0 - mean * C0) + E0 + gate_b[0];
        const float l1 = rstd * (a1 - mean * C1) + E1 + gate_b[1];
        const float mx = fmaxf(l0, l1);
        const float e0 = __expf(l0 - mx), e1 = __expf(l1 - mx);
        const float inv = 1.f / (e0 + e1);
        float2 w;
        w.x = e0 * inv;
        w.y = e1 * inv;
        ((float2*)gate_ws)[row] = w;
    }
}

// ---------------- Pass B: elementwise blend (pure copy stream) -------------
// Grid-stride, 2 rows per wave per iter. seq/msa re-reads hit L3 (resident
// from pass A). Nontemporal stores: output is never re-read by us.
__global__ __launch_bounds__(256) void blend_kernel(
    const float* __restrict__ seq, const float* __restrict__ msa,
    const float* __restrict__ gate_ws, float* __restrict__ out,
    int nrows, int nwaves)
{
    const int lane = threadIdx.x & 63;
    const int wid  = (int)((blockIdx.x * blockDim.x + threadIdx.x) >> 6);
    const float2* gw = (const float2*)gate_ws;

    for (int base = wid * 2; base < nrows; base += nwaves * 2) {
        const int r0 = base;
        const bool has1 = (base + 1) < nrows;
        const int r1 = has1 ? (base + 1) : base;

        const f4* s0p = (const f4*)(seq + (size_t)r0 * D);
        const f4* m0p = (const f4*)(msa + (size_t)r0 * D);
        const f4* s1p = (const f4*)(seq + (size_t)r1 * D);
        const f4* m1p = (const f4*)(msa + (size_t)r1 * D);

        // all loads up front
        const float2 w0 = gw[r0];
        const float2 w1 = gw[r1];
        f4 s0[3], m0[3], s1[3], m1[3];
        #pragma unroll
        for (int j = 0; j < 3; ++j) {
            s0[j] = s0p[j * 64 + lane];
            m0[j] = m0p[j * 64 + lane];
            s1[j] = s1p[j * 64 + lane];
            m1[j] = m1p[j * 64 + lane];
        }

        f4* o0 = (f4*)(out + (size_t)r0 * D);
        #pragma unroll
        for (int j = 0; j < 3; ++j) {
            f4 o = w0.x * s0[j] + w0.y * m0[j];
            __builtin_nontemporal_store(o, &o0[j * 64 + lane]);
        }
        if (has1) {
            f4* o1 = (f4*)(out + (size_t)r1 * D);
            #pragma unroll
            for (int j = 0; j < 3; ++j) {
                f4 o = w1.x * s1[j] + w1.y * m1[j];
                __builtin_nontemporal_store(o, &o1[j * 64 + lane]);
            }
        }
    }
}

extern "C" void kernel_launch(void* const* d_in, const int* in_sizes, int n_in,
                              void* d_out, int out_size, void* d_ws, size_t ws_size,
                              hipStream_t stream) {
    const float* seq    = (const float*)d_in[0];
    const float* msa    = (const float*)d_in[1];
    const float* gamma  = (const float*)d_in[2];
    const float* beta   = (const float*)d_in[3];
    const float* gate_w = (const float*)d_in[4];
    const float* gate_b = (const float*)d_in[5];
    float* out = (float*)d_out;
    float* ws  = (float*)d_ws;

    const int nrows = in_sizes[0] / D;              // 16384
    stats_kernel<<<(nrows + 3) / 4, 256, 0, stream>>>(
        seq, msa, gamma, beta, gate_w, gate_b, ws, nrows);
    const int blocks = 2048;                        // 8192 waves, 2 rows each
    const int nwaves = blocks * 4;
    blend_kernel<<<blocks, 256, 0, stream>>>(seq, msa, ws, out, nrows, nwaves);
}